// Round 6
// baseline (365479.175 us; speedup 1.0000x reference)
//
#include <hip/hip_runtime.h>
#include <math.h>

// ---------------- problem constants ----------------
#define K_BEAM  10
#define V_SZ    50257
#define E_SZ    128
#define H1_SZ   128
#define H2_SZ   64
#define Q_SZ    64
#define T_SZ    2048
#define MAXLEN  30
#define SEQ_LEN 31
#define SOS_TOK 1
#define EOS_TOK 2
#define NEGD    (-1e30)

#define CB 128              // blocks in logits kernel
#define VC 393              // ceil(V_SZ / CB)

// ---------------- workspace layout (float indices; f64 slots on even idx) ----
#define ST_A_F   0          // double[4480]: h1[10][128],c1,h2[10][64],c2,ctx
#define ST_B_F   8960
#define SD_H1    0
#define SD_C1    1280
#define SD_H2    2560
#define SD_C2    3200
#define SD_CTX   3840
#define META_A_F 17920      // SC double[10](+0..20f), FIN i32[10](+20), PREV i32[10](+30), SEQ i32[10][31](+40)
#define META_B_F 18272
#define M_SC     0
#define M_FIN    20
#define M_PREV   30
#define M_SEQ    40
#define XVEC_F   18624      // double[10][128] = 2560 floats
#define PICKV_F  21184      // double[10]
#define PICKF_F  21204      // int[10]
#define LOGITS_F 21248      // float[10][50257]
#define WS_NEED_BYTES ((size_t)(LOGITS_F + K_BEAM*V_SZ + 16) * 4)

// ---------------- init ----------------
__global__ void init_kernel(float* ws) {
  const int tid = threadIdx.x;
  double* stA = (double*)(ws + ST_A_F);
  for (int i = tid; i < 4480; i += 256) stA[i] = 0.0;
  float* mA = ws + META_A_F;
  if (tid < K_BEAM) {
    ((double*)(mA + M_SC))[tid] = 0.0;
    ((int*)(mA + M_FIN))[tid] = 0;
    ((int*)(mA + M_PREV))[tid] = SOS_TOK;
  }
  for (int i = tid; i < K_BEAM*SEQ_LEN; i += 256)
    ((int*)(mA + M_SEQ))[i] = SOS_TOK;
}

// ---------------- forward: gather + LSTMx2 + attention (single block, f64) ----
__global__ __launch_bounds__(256) void fwd_kernel(
    float* ws, int step,
    const float* enc_key, const float* enc_values, const float* maskp,
    const float* embedding,
    const float* W_ih1, const float* W_hh1, const float* b_ih1, const float* b_hh1,
    const float* W_ih2, const float* W_hh2, const float* b_ih2, const float* b_hh2,
    const float* Wq, const float* bq) {
  const int tid = threadIdx.x;
  const int par = step & 1;
  const double* S = (const double*)(ws + (par == 0 ? ST_A_F : ST_B_F));
  double*       D = (double*)(ws + (par == 0 ? ST_B_F : ST_A_F));
  const float* msrc = ws + (par == 0 ? META_A_F : META_B_F);
  float*       mdst = ws + (par == 0 ? META_B_F : META_A_F);
  double* xvec = (double*)(ws + XVEC_F);

  __shared__ int s_pb[K_BEAM], s_tok[K_BEAM];
  if (tid < K_BEAM) {
    int pb, tok, fin; double sc;
    if (step == 0) {
      pb = tid; tok = ((const int*)(msrc + M_PREV))[tid];
      sc = ((const double*)(msrc + M_SC))[tid];
      fin = ((const int*)(msrc + M_FIN))[tid];
    } else {
      int f = ((const int*)(ws + PICKF_F))[tid];
      pb = f / V_SZ; tok = f - pb * V_SZ;
      pb = min(max(pb, 0), K_BEAM - 1);
      tok = min(max(tok, 0), V_SZ - 1);
      sc = ((const double*)(ws + PICKV_F))[tid];
      fin = ((const int*)(msrc + M_FIN))[pb] | (tok == EOS_TOK);
    }
    s_pb[tid] = pb; s_tok[tid] = tok;
    ((double*)(mdst + M_SC))[tid] = sc;
    ((int*)(mdst + M_FIN))[tid] = fin;
    ((int*)(mdst + M_PREV))[tid] = tok;
  }
  __syncthreads();
  for (int t = tid; t < K_BEAM*SEQ_LEN; t += 256) {
    int j = t / SEQ_LEN, p = t - j*SEQ_LEN;
    int v = ((const int*)(msrc + M_SEQ))[s_pb[j]*SEQ_LEN + p];
    if (step > 0 && p == step) v = s_tok[j];
    ((int*)(mdst + M_SEQ))[t] = v;
  }
  __syncthreads();

  __shared__ double xin[E_SZ+Q_SZ], h1p[H1_SZ], h2pd[H2_SZ], gt[4*H1_SZ],
                    h1n[H1_SZ], h2n[H2_SZ], qd[Q_SZ], red[256];
  __shared__ double eng[T_SZ];

  for (int b = 0; b < K_BEAM; ++b) {
    const int pb = s_pb[b], tok = s_tok[b];
    if (tid < E_SZ)  xin[tid] = (double)embedding[(size_t)tok*E_SZ + tid];
    if (tid < Q_SZ)  xin[E_SZ + tid] = S[SD_CTX + pb*Q_SZ + tid];
    if (tid < H1_SZ) h1p[tid] = S[SD_H1 + pb*H1_SZ + tid];
    if (tid < H2_SZ) h2pd[tid] = S[SD_H2 + pb*H2_SZ + tid];
    __syncthreads();
    // LSTM1 gates
    for (int r = tid; r < 4*H1_SZ; r += 256) {
      double acc = (double)b_ih1[r] + (double)b_hh1[r];
      const float* wi = W_ih1 + (size_t)r*(E_SZ+Q_SZ);
      for (int j = 0; j < E_SZ+Q_SZ; ++j) acc += (double)wi[j] * xin[j];
      const float* wh = W_hh1 + (size_t)r*H1_SZ;
      for (int j = 0; j < H1_SZ; ++j) acc += (double)wh[j] * h1p[j];
      gt[r] = acc;
    }
    __syncthreads();
    if (tid < H1_SZ) {
      double ig = 1.0/(1.0+exp(-gt[tid]));
      double fg = 1.0/(1.0+exp(-gt[H1_SZ+tid]));
      double gg = tanh(gt[2*H1_SZ+tid]);
      double og = 1.0/(1.0+exp(-gt[3*H1_SZ+tid]));
      double c = fg * S[SD_C1 + pb*H1_SZ + tid] + ig*gg;
      double h = og * tanh(c);
      D[SD_C1 + b*H1_SZ + tid] = c; D[SD_H1 + b*H1_SZ + tid] = h;
      h1n[tid] = h;
    }
    __syncthreads();
    // LSTM2 gates (256 = 4*H2)
    {
      int r = tid;
      double acc = (double)b_ih2[r] + (double)b_hh2[r];
      const float* wi = W_ih2 + (size_t)r*H1_SZ;
      for (int j = 0; j < H1_SZ; ++j) acc += (double)wi[j] * h1n[j];
      const float* wh = W_hh2 + (size_t)r*H2_SZ;
      for (int j = 0; j < H2_SZ; ++j) acc += (double)wh[j] * h2pd[j];
      gt[r] = acc;
    }
    __syncthreads();
    if (tid < H2_SZ) {
      double ig = 1.0/(1.0+exp(-gt[tid]));
      double fg = 1.0/(1.0+exp(-gt[H2_SZ+tid]));
      double gg = tanh(gt[2*H2_SZ+tid]);
      double og = 1.0/(1.0+exp(-gt[3*H2_SZ+tid]));
      double c = fg * S[SD_C2 + pb*H2_SZ + tid] + ig*gg;
      double h = og * tanh(c);
      D[SD_C2 + b*H2_SZ + tid] = c; D[SD_H2 + b*H2_SZ + tid] = h;
      h2n[tid] = h;
      xvec[b*128 + tid] = h;
    }
    __syncthreads();
    if (tid < Q_SZ) {
      double acc = (double)bq[tid];
      const float* wr = Wq + (size_t)tid*H2_SZ;
      for (int j = 0; j < H2_SZ; ++j) acc += (double)wr[j] * h2n[j];
      qd[tid] = acc;
    }
    __syncthreads();
    // attention: energy, softmax, mask, renorm, ctx — literal
    double lm = -1e300;
    for (int t = tid; t < T_SZ; t += 256) {
      const float* kr = enc_key + (size_t)t*Q_SZ;
      double e = 0.0;
      for (int j = 0; j < Q_SZ; ++j) e += (double)kr[j] * qd[j];
      eng[t] = e; lm = fmax(lm, e);
    }
    red[tid] = lm; __syncthreads();
    for (int s2 = 128; s2 > 0; s2 >>= 1) { if (tid < s2) red[tid] = fmax(red[tid], red[tid+s2]); __syncthreads(); }
    double mx = red[0]; __syncthreads();
    double ls = 0.0;
    for (int t = tid; t < T_SZ; t += 256) ls += exp(eng[t] - mx);
    red[tid] = ls; __syncthreads();
    for (int s2 = 128; s2 > 0; s2 >>= 1) { if (tid < s2) red[tid] += red[tid+s2]; __syncthreads(); }
    double Ssum = red[0]; __syncthreads();
    double lm2 = 0.0;
    for (int t = tid; t < T_SZ; t += 256) {
      double matt = (double)maskp[t] * (exp(eng[t] - mx) / Ssum);
      eng[t] = matt; lm2 += matt;
    }
    red[tid] = lm2; __syncthreads();
    for (int s2 = 128; s2 > 0; s2 >>= 1) { if (tid < s2) red[tid] += red[tid+s2]; __syncthreads(); }
    double msum = fmax(red[0], 2e-30); __syncthreads();
    int v = tid & 63, g4 = tid >> 6;
    double acc = 0.0;
    for (int t = g4; t < T_SZ; t += 4) acc += eng[t] * (double)enc_values[(size_t)t*Q_SZ + v];
    red[tid] = acc; __syncthreads();
    if (g4 == 0) {
      double cv = (red[v] + red[64+v] + red[128+v] + red[192+v]) / msum;
      D[SD_CTX + b*Q_SZ + v] = cv;
      xvec[b*128 + 64 + v] = cv;
    }
    __syncthreads();
  }
}

// ---------------- logits: each element an independent f64 dot (deterministic) --
__global__ __launch_bounds__(256) void logits_kernel(float* ws, const float* Wc, const float* bc) {
  const int tid = threadIdx.x, bb = blockIdx.x;
  const int v0 = bb*VC, vn = min(VC, V_SZ - v0);
  __shared__ double xs[K_BEAM*128];
  const double* xvec = (const double*)(ws + XVEC_F);
  for (int i = tid; i < K_BEAM*128; i += 256) xs[i] = xvec[i];
  __syncthreads();
  float* lg = ws + LOGITS_F;
  for (int vl = tid; vl < vn; vl += 256) {
    const float* wr = Wc + (size_t)(v0+vl)*128;
    double acc[K_BEAM];
    #pragma unroll
    for (int b = 0; b < K_BEAM; ++b) acc[b] = 0.0;
    for (int d = 0; d < 128; ++d) {
      double w = (double)wr[d];
      #pragma unroll
      for (int b = 0; b < K_BEAM; ++b) acc[b] += w * xs[b*128 + d];
    }
    double bcv = (double)bc[v0+vl];
    #pragma unroll
    for (int b = 0; b < K_BEAM; ++b)
      lg[(size_t)b*V_SZ + v0 + vl] = (float)(acc[b] + bcv);
  }
}

// ---------------- pick: literal log_softmax + 10x argmax over all k*V ---------
__global__ __launch_bounds__(256) void pick_kernel(float* ws, int step) {
  const int tid = threadIdx.x;
  const int par = step & 1;
  const float* mcur = ws + (par == 0 ? META_B_F : META_A_F);  // written by fwd(step)
  const float* lg = ws + LOGITS_F;
  __shared__ double sc[K_BEAM], lse[K_BEAM];
  __shared__ int fin[K_BEAM];
  __shared__ double sred[256]; __shared__ int sidx[256];
  __shared__ double pv[K_BEAM]; __shared__ int pf[K_BEAM];
  if (tid < K_BEAM) {
    sc[tid]  = ((const double*)(mcur + M_SC))[tid];
    fin[tid] = ((const int*)(mcur + M_FIN))[tid];
  }
  __syncthreads();
  // per-beam logsumexp over full row
  for (int b = 0; b < K_BEAM; ++b) {
    const float* row = lg + (size_t)b*V_SZ;
    double lm = -1e300;
    for (int v = tid; v < V_SZ; v += 256) lm = fmax(lm, (double)row[v]);
    sred[tid] = lm; __syncthreads();
    for (int s2 = 128; s2 > 0; s2 >>= 1) { if (tid < s2) sred[tid] = fmax(sred[tid], sred[tid+s2]); __syncthreads(); }
    double mx = sred[0]; __syncthreads();
    double s = 0.0;
    for (int v = tid; v < V_SZ; v += 256) s += exp((double)row[v] - mx);
    sred[tid] = s; __syncthreads();
    for (int s2 = 128; s2 > 0; s2 >>= 1) { if (tid < s2) sred[tid] += sred[tid+s2]; __syncthreads(); }
    if (tid == 0) lse[b] = mx + log(sred[0]);
    __syncthreads();
  }
  // 10 argmax rounds; ties -> lower flat index; exclusion by flat
  for (int pick = 0; pick < K_BEAM; ++pick) {
    double bv = -1e301; int bf = 0x7fffffff;
    for (int b = 0; b < K_BEAM; ++b) {
      if (fin[b]) continue;                 // finished: handled as single cand below
      if (step == 0 && b > 0) continue;     // masked: single NEG cand below
      const double base = sc[b] - lse[b];
      const float* row = lg + (size_t)b*V_SZ;
      for (int v = tid; v < V_SZ; v += 256) {
        int flat = b*V_SZ + v;
        bool ex = false;
        for (int q = 0; q < pick; ++q) ex = ex || (pf[q] == flat);
        if (ex) continue;
        double val = base + (double)row[v];
        if (val > bv || (val == bv && flat < bf)) { bv = val; bf = flat; }
      }
    }
    if (tid == 0) {
      for (int b = 0; b < K_BEAM; ++b) {
        double val; int flat;
        if (fin[b])                    { val = sc[b]; flat = b*V_SZ + EOS_TOK; }
        else if (step == 0 && b > 0)   { val = NEGD;  flat = b*V_SZ; }
        else continue;
        bool ex = false;
        for (int q = 0; q < pick; ++q) ex = ex || (pf[q] == flat);
        if (!ex && (val > bv || (val == bv && flat < bf))) { bv = val; bf = flat; }
      }
    }
    sred[tid] = bv; sidx[tid] = bf; __syncthreads();
    for (int s2 = 128; s2 > 0; s2 >>= 1) {
      if (tid < s2) {
        if (sred[tid+s2] > sred[tid] ||
            (sred[tid+s2] == sred[tid] && sidx[tid+s2] < sidx[tid])) {
          sred[tid] = sred[tid+s2]; sidx[tid] = sidx[tid+s2];
        }
      }
      __syncthreads();
    }
    if (tid == 0) { pv[pick] = sred[0]; pf[pick] = sidx[0]; }
    __syncthreads();
  }
  if (tid < K_BEAM) {
    ((double*)(ws + PICKV_F))[tid] = pv[tid];
    ((int*)(ws + PICKF_F))[tid] = pf[tid];
  }
}

// ---------------- final: gather + lengths + output ----------------
__global__ __launch_bounds__(256) void final_kernel(float* ws, float* out) {
  const int tid = threadIdx.x;
  const float* mA = ws + META_A_F;     // dst of step 29 (odd step -> dst = A)
  const int* seqA = (const int*)(mA + M_SEQ);
  const double* pvv = (const double*)(ws + PICKV_F);
  const int* pfv = (const int*)(ws + PICKF_F);
  __shared__ int seqF[K_BEAM*SEQ_LEN];
  __shared__ int s_tok[K_BEAM], s_pb[K_BEAM];
  if (tid < K_BEAM) {
    int f = pfv[tid];
    int pb = f / V_SZ, tk = f - pb*V_SZ;
    pb = min(max(pb, 0), K_BEAM - 1);
    tk = min(max(tk, 0), V_SZ - 1);
    s_pb[tid] = pb; s_tok[tid] = tk;
  }
  __syncthreads();
  for (int t = tid; t < K_BEAM*SEQ_LEN; t += 256) {
    int j = t / SEQ_LEN, p = t - j*SEQ_LEN;
    seqF[t] = (p == MAXLEN) ? s_tok[j] : seqA[s_pb[j]*SEQ_LEN + p];
  }
  __syncthreads();
  if (tid < K_BEAM) {
    int first = -1;
    for (int p = 1; p <= MAXLEN; ++p)
      if (seqF[tid*SEQ_LEN + p] == EOS_TOK) { first = p - 1; break; }
    double len = (first >= 0) ? (double)(first + 2) : (double)(MAXLEN + 2);
    double scv = pvv[tid];
    out[K_BEAM*SEQ_LEN + tid] = (float)scv;
    out[K_BEAM*SEQ_LEN + K_BEAM + tid] = (float)(scv / pow(len, 1.2));
  }
  for (int t = tid; t < K_BEAM*SEQ_LEN; t += 256) out[t] = (float)seqF[t];
}

// ---------------- probe stamp ----------------
__global__ void probe_kernel(float* out, float code) { out[0] = code; }

// ---------------- host ----------------
extern "C" void kernel_launch(void* const* d_in, const int* in_sizes, int n_in,
                              void* d_out, int out_size, void* d_ws, size_t ws_size,
                              hipStream_t stream) {
  const float* enc_key    = (const float*)d_in[0];
  const float* enc_values = (const float*)d_in[1];
  const float* maskp      = (const float*)d_in[2];
  const float* embedding  = (const float*)d_in[3];
  const float* W_ih1      = (const float*)d_in[4];
  const float* W_hh1      = (const float*)d_in[5];
  const float* b_ih1      = (const float*)d_in[6];
  const float* b_hh1      = (const float*)d_in[7];
  const float* W_ih2      = (const float*)d_in[8];
  const float* W_hh2      = (const float*)d_in[9];
  const float* b_ih2      = (const float*)d_in[10];
  const float* b_hh2      = (const float*)d_in[11];
  const float* Wq         = (const float*)d_in[12];
  const float* bq         = (const float*)d_in[13];
  const float* Wc         = (const float*)d_in[14];
  const float* bc         = (const float*)d_in[15];
  float* ws  = (float*)d_ws;
  float* out = (float*)d_out;

  static const int EXP_SIZES[16] = {
    T_SZ*Q_SZ, T_SZ*Q_SZ, T_SZ, V_SZ*E_SZ,
    4*H1_SZ*(E_SZ+Q_SZ), 4*H1_SZ*H1_SZ, 4*H1_SZ, 4*H1_SZ,
    4*H2_SZ*H1_SZ, 4*H2_SZ*H2_SZ, 4*H2_SZ, 4*H2_SZ,
    Q_SZ*H2_SZ, Q_SZ, V_SZ*(H2_SZ+Q_SZ), V_SZ };
  float code = 0.f;
  if (n_in != 16) code = 3e6f + (float)n_in * 1000.f;
  else {
    for (int i = 0; i < 16; ++i)
      if (in_sizes[i] != EXP_SIZES[i]) { code = 5e6f + i*10000.f + (float)(in_sizes[i] % 9999); break; }
  }
  if (code == 0.f && out_size != K_BEAM*SEQ_LEN + 2*K_BEAM) code = 4e6f + (float)out_size;
  if (code == 0.f && ws_size < WS_NEED_BYTES) {
    size_t kb = ws_size / 1024; if (kb > 899999) kb = 899999;
    code = 2e6f + (float)kb;          // ws too small: exfiltrate its size in KB
  }

  if (code == 0.f) {
    init_kernel<<<1, 256, 0, stream>>>(ws);
    for (int i = 0; i < MAXLEN; ++i) {
      fwd_kernel<<<1, 256, 0, stream>>>(ws, i, enc_key, enc_values, maskp, embedding,
                                        W_ih1, W_hh1, b_ih1, b_hh1,
                                        W_ih2, W_hh2, b_ih2, b_hh2, Wq, bq);
      logits_kernel<<<CB, 256, 0, stream>>>(ws, Wc, bc);
      pick_kernel<<<1, 256, 0, stream>>>(ws, i);
    }
    final_kernel<<<1, 256, 0, stream>>>(ws, out);
  } else {
    probe_kernel<<<1, 1, 0, stream>>>(out, code);
  }
}

// Round 7
// 18422.050 us; speedup vs baseline: 19.8392x; 19.8392x over previous
//
#include <hip/hip_runtime.h>
#include <math.h>

// ---------------- problem constants ----------------
#define K_BEAM  10
#define V_SZ    50257
#define E_SZ    128
#define H1_SZ   128
#define H2_SZ   64
#define Q_SZ    64
#define T_SZ    2048
#define MAXLEN  30
#define SEQ_LEN 31
#define SOS_TOK 1
#define EOS_TOK 2
#define NEGD    (-1e30)

#define CB 128              // blocks in c_kernel
#define VC 393              // ceil(V_SZ / CB)
#define NREAL (CB*K_BEAM*10)            // 12800 staged candidates
#define NCAND (NREAL + K_BEAM)          // + finished-beam EOS candidates

// ---------------- workspace layout (float indices; doubles on even idx) ------
#define ST_A_F   0          // double[4480]: h1[10][128],c1[10][128],h2[10][64],c2,ctx
#define ST_B_F   8960
#define SD_H1    0
#define SD_C1    1280
#define SD_H2    2560
#define SD_C2    3200
#define SD_CTX   3840
#define META_A_F 17920      // SC double[10](@0), FIN i32[10](@20), PREV i32[10](@30), SEQ i32[10][31](@40)
#define META_B_F 18272
#define M_SC     0
#define M_FIN    20
#define M_PREV   30
#define M_SEQ    40
#define XVEC_F   18624      // double[10][128]
#define PICKV_F  21184      // double[10]
#define PICKF_F  21204      // int[10]
#define LSEM_F   21216      // double[128][10] partial max
#define LSES_F   23776      // double[128][10] partial sumexp
#define CANDV_F  26336      // float[128][10][10] candidate logits (f32-rounded)
#define CANDI_F  39136      // int[128][10][10] candidate v indices
// total 51936 floats ~= 208 KiB (r6 verified ws >= 2.1 MB)

// ---------------- wave helpers (f64) ----------------
__device__ __forceinline__ void wave_merge_ms_d(double& m, double& s) {
  #pragma unroll
  for (int off = 32; off > 0; off >>= 1) {
    double om = __shfl_down(m, off, 64);
    double os = __shfl_down(s, off, 64);
    double nm = fmax(m, om);
    s = s * exp(m - nm) + os * exp(om - nm);
    m = nm;
  }
}
// argmax: higher value wins; tie -> lower index (jax top_k order)
__device__ __forceinline__ void wave_argmax_f(float& v, int& i) {
  #pragma unroll
  for (int off = 32; off > 0; off >>= 1) {
    float ov = __shfl_down(v, off, 64);
    int   oi = __shfl_down(i, off, 64);
    if (ov > v || (ov == v && oi < i)) { v = ov; i = oi; }
  }
}

// ---------------- init ----------------
__global__ void init_kernel(float* ws) {
  const int tid = threadIdx.x;
  double* stA = (double*)(ws + ST_A_F);
  for (int i = tid; i < 4480; i += 256) stA[i] = 0.0;
  float* mA = ws + META_A_F;
  if (tid < K_BEAM) {
    ((double*)(mA + M_SC))[tid] = 0.0;
    ((int*)(mA + M_FIN))[tid] = 0;
    ((int*)(mA + M_PREV))[tid] = SOS_TOK;
  }
  for (int i = tid; i < K_BEAM*SEQ_LEN; i += 256)
    ((int*)(mA + M_SEQ))[i] = SOS_TOK;
}

// ---------------- per-beam forward: gather + LSTMx2 + attention (f64) --------
__global__ __launch_bounds__(256) void ab_kernel(
    float* ws, int step,
    const float* enc_key, const float* enc_values, const float* maskp,
    const float* embedding,
    const float* W_ih1, const float* W_hh1, const float* b_ih1, const float* b_hh1,
    const float* W_ih2, const float* W_hh2, const float* b_ih2, const float* b_hh2,
    const float* Wq, const float* bq) {
  const int tid = threadIdx.x;
  const int b = blockIdx.x;
  const int par = step & 1;
  const double* S = (const double*)(ws + (par == 0 ? ST_A_F : ST_B_F));
  double*       D = (double*)(ws + (par == 0 ? ST_B_F : ST_A_F));
  const float* msrc = ws + (par == 0 ? META_A_F : META_B_F);
  float*       mdst = ws + (par == 0 ? META_B_F : META_A_F);
  double* xvec = (double*)(ws + XVEC_F);

  __shared__ int s_pb, s_tok;
  if (tid == 0) {
    int pb, tok, fin; double sc;
    if (step == 0) {
      pb = b; tok = ((const int*)(msrc + M_PREV))[b];
      sc = ((const double*)(msrc + M_SC))[b];
      fin = ((const int*)(msrc + M_FIN))[b];
    } else {
      int f = ((const int*)(ws + PICKF_F))[b];
      pb = f / V_SZ; tok = f - pb * V_SZ;
      pb = min(max(pb, 0), K_BEAM - 1);
      tok = min(max(tok, 0), V_SZ - 1);
      sc = ((const double*)(ws + PICKV_F))[b];
      fin = ((const int*)(msrc + M_FIN))[pb] | (tok == EOS_TOK);
    }
    s_pb = pb; s_tok = tok;
    ((double*)(mdst + M_SC))[b] = sc;
    ((int*)(mdst + M_FIN))[b] = fin;
    ((int*)(mdst + M_PREV))[b] = tok;
  }
  __syncthreads();
  const int pb = s_pb, tok = s_tok;
  for (int p = tid; p < SEQ_LEN; p += 256) {
    int v = ((const int*)(msrc + M_SEQ))[pb*SEQ_LEN + p];
    if (step > 0 && p == step) v = tok;
    ((int*)(mdst + M_SEQ))[b*SEQ_LEN + p] = v;
  }

  __shared__ double xin[E_SZ+Q_SZ], h1p[H1_SZ], h2pd[H2_SZ], gt[4*H1_SZ],
                    h1n[H1_SZ], h2n[H2_SZ], qd[Q_SZ], red[256];
  __shared__ double eng[T_SZ];

  if (tid < E_SZ)  xin[tid] = (double)embedding[(size_t)tok*E_SZ + tid];
  if (tid < Q_SZ)  xin[E_SZ + tid] = S[SD_CTX + pb*Q_SZ + tid];
  if (tid < H1_SZ) h1p[tid] = S[SD_H1 + pb*H1_SZ + tid];
  if (tid < H2_SZ) h2pd[tid] = S[SD_H2 + pb*H2_SZ + tid];
  __syncthreads();
  // LSTM1 gates (identical loop order to verified r6 build)
  for (int r = tid; r < 4*H1_SZ; r += 256) {
    double acc = (double)b_ih1[r] + (double)b_hh1[r];
    const float* wi = W_ih1 + (size_t)r*(E_SZ+Q_SZ);
    for (int j = 0; j < E_SZ+Q_SZ; ++j) acc += (double)wi[j] * xin[j];
    const float* wh = W_hh1 + (size_t)r*H1_SZ;
    for (int j = 0; j < H1_SZ; ++j) acc += (double)wh[j] * h1p[j];
    gt[r] = acc;
  }
  __syncthreads();
  if (tid < H1_SZ) {
    double ig = 1.0/(1.0+exp(-gt[tid]));
    double fg = 1.0/(1.0+exp(-gt[H1_SZ+tid]));
    double gg = tanh(gt[2*H1_SZ+tid]);
    double og = 1.0/(1.0+exp(-gt[3*H1_SZ+tid]));
    double c = fg * S[SD_C1 + pb*H1_SZ + tid] + ig*gg;
    double h = og * tanh(c);
    D[SD_C1 + b*H1_SZ + tid] = c; D[SD_H1 + b*H1_SZ + tid] = h;
    h1n[tid] = h;
  }
  __syncthreads();
  // LSTM2 gates
  {
    int r = tid;
    double acc = (double)b_ih2[r] + (double)b_hh2[r];
    const float* wi = W_ih2 + (size_t)r*H1_SZ;
    for (int j = 0; j < H1_SZ; ++j) acc += (double)wi[j] * h1n[j];
    const float* wh = W_hh2 + (size_t)r*H2_SZ;
    for (int j = 0; j < H2_SZ; ++j) acc += (double)wh[j] * h2pd[j];
    gt[r] = acc;
  }
  __syncthreads();
  if (tid < H2_SZ) {
    double ig = 1.0/(1.0+exp(-gt[tid]));
    double fg = 1.0/(1.0+exp(-gt[H2_SZ+tid]));
    double gg = tanh(gt[2*H2_SZ+tid]);
    double og = 1.0/(1.0+exp(-gt[3*H2_SZ+tid]));
    double c = fg * S[SD_C2 + pb*H2_SZ + tid] + ig*gg;
    double h = og * tanh(c);
    D[SD_C2 + b*H2_SZ + tid] = c; D[SD_H2 + b*H2_SZ + tid] = h;
    h2n[tid] = h;
    xvec[b*128 + tid] = h;
  }
  __syncthreads();
  if (tid < Q_SZ) {
    double acc = (double)bq[tid];
    const float* wr = Wq + (size_t)tid*H2_SZ;
    for (int j = 0; j < H2_SZ; ++j) acc += (double)wr[j] * h2n[j];
    qd[tid] = acc;
  }
  __syncthreads();
  // attention (literal: softmax, mask, renorm)
  double lm = -1e300;
  for (int t = tid; t < T_SZ; t += 256) {
    const float* kr = enc_key + (size_t)t*Q_SZ;
    double e = 0.0;
    for (int j = 0; j < Q_SZ; ++j) e += (double)kr[j] * qd[j];
    eng[t] = e; lm = fmax(lm, e);
  }
  red[tid] = lm; __syncthreads();
  for (int s2 = 128; s2 > 0; s2 >>= 1) { if (tid < s2) red[tid] = fmax(red[tid], red[tid+s2]); __syncthreads(); }
  double mx = red[0]; __syncthreads();
  double ls = 0.0;
  for (int t = tid; t < T_SZ; t += 256) ls += exp(eng[t] - mx);
  red[tid] = ls; __syncthreads();
  for (int s2 = 128; s2 > 0; s2 >>= 1) { if (tid < s2) red[tid] += red[tid+s2]; __syncthreads(); }
  double Ssum = red[0]; __syncthreads();
  double lm2 = 0.0;
  for (int t = tid; t < T_SZ; t += 256) {
    double matt = (double)maskp[t] * (exp(eng[t] - mx) / Ssum);
    eng[t] = matt; lm2 += matt;
  }
  red[tid] = lm2; __syncthreads();
  for (int s2 = 128; s2 > 0; s2 >>= 1) { if (tid < s2) red[tid] += red[tid+s2]; __syncthreads(); }
  double msum = fmax(red[0], 2e-30); __syncthreads();
  int v = tid & 63, g4 = tid >> 6;
  double acc = 0.0;
  for (int t = g4; t < T_SZ; t += 4) acc += eng[t] * (double)enc_values[(size_t)t*Q_SZ + v];
  red[tid] = acc; __syncthreads();
  if (g4 == 0) {
    double cv = (red[v] + red[64+v] + red[128+v] + red[192+v]) / msum;
    D[SD_CTX + b*Q_SZ + v] = cv;
    xvec[b*128 + 64 + v] = cv;
  }
}

// ---------------- logits chunk + lse partials + per-beam block top-10 --------
__global__ __launch_bounds__(256) void c_kernel(float* ws, const float* Wc, const float* bc) {
  const int tid = threadIdx.x, bb = blockIdx.x;
  const int v0 = bb*VC, vn = min(VC, V_SZ - v0);
  __shared__ double xs[K_BEAM*128];
  __shared__ float lg[VC*K_BEAM];
  const double* xvec = (const double*)(ws + XVEC_F);
  for (int i = tid; i < K_BEAM*128; i += 256) xs[i] = xvec[i];
  __syncthreads();
  // same per-element serial d-loop as the verified build -> bit-identical logits
  for (int vl = tid; vl < vn; vl += 256) {
    const float* wr = Wc + (size_t)(v0+vl)*128;
    double acc[K_BEAM];
    #pragma unroll
    for (int b = 0; b < K_BEAM; ++b) acc[b] = 0.0;
    for (int d = 0; d < 128; ++d) {
      double w = (double)wr[d];
      #pragma unroll
      for (int b = 0; b < K_BEAM; ++b) acc[b] += w * xs[b*128 + d];
    }
    double bcv = (double)bc[v0+vl];
    #pragma unroll
    for (int b = 0; b < K_BEAM; ++b) lg[vl*K_BEAM + b] = (float)(acc[b] + bcv);
  }
  __syncthreads();

  const int lane = tid & 63, w = tid >> 6;
  double* lse_m = (double*)(ws + LSEM_F);
  double* lse_s = (double*)(ws + LSES_F);
  float*  cvv   = ws + CANDV_F;
  int*    cii   = (int*)(ws + CANDI_F);
  for (int b = w; b < K_BEAM; b += 4) {
    // f64 partial logsumexp over this chunk
    double m = -1e300, s = 0.0;
    for (int vl = lane; vl < vn; vl += 64) {
      double val = (double)lg[vl*K_BEAM + b];
      double nm = fmax(m, val);
      s = s * exp(m - nm) + exp(val - nm);
      m = nm;
    }
    wave_merge_ms_d(m, s);
    if (lane == 0) { lse_m[bb*K_BEAM + b] = m; lse_s[bb*K_BEAM + b] = s; }
    // block-local per-beam top-10 (tie -> lower v), exclusion by index
    int taken[10];
    for (int pick = 0; pick < 10; ++pick) {
      float bv = -3e38f; int bi = 0x7ffffff0;
      for (int vl = lane; vl < vn; vl += 64) {
        bool skip = false;
        for (int q = 0; q < pick; ++q) skip = skip || (taken[q] == vl);
        if (!skip) {
          float val = lg[vl*K_BEAM + b];
          if (val > bv || (val == bv && vl < bi)) { bv = val; bi = vl; }
        }
      }
      float wv = bv; int wi = bi;
      wave_argmax_f(wv, wi);
      wv = __shfl(wv, 0, 64); wi = __shfl(wi, 0, 64);
      taken[pick] = wi;
      wi = min(max(wi, 0), vn - 1);
      if (lane == 0) {
        cvv[(bb*K_BEAM + b)*10 + pick] = wv;
        cii[(bb*K_BEAM + b)*10 + pick] = v0 + wi;
      }
    }
  }
}

// ---------------- selection merge (f64) ----------------
__global__ __launch_bounds__(256) void sel_kernel(float* ws, int step) {
  const int tid = threadIdx.x;
  const int par = step & 1;
  const float* mcur = ws + (par == 0 ? META_B_F : META_A_F);  // written by ab(step)
  __shared__ double scS[K_BEAM], lseS[K_BEAM];
  __shared__ int finS[K_BEAM];
  __shared__ double sred[256]; __shared__ int sidx[256];
  __shared__ double pv[K_BEAM]; __shared__ int pf[K_BEAM];
  if (tid < K_BEAM) {
    scS[tid]  = ((const double*)(mcur + M_SC))[tid];
    finS[tid] = ((const int*)(mcur + M_FIN))[tid];
  }
  __syncthreads();
  // merge 128 lse partials per beam
  {
    const double* lse_m = (const double*)(ws + LSEM_F);
    const double* lse_s = (const double*)(ws + LSES_F);
    const int lane = tid & 63, w = tid >> 6;
    for (int b = w; b < K_BEAM; b += 4) {
      double m = -1e300, s = 0.0;
      #pragma unroll
      for (int r = 0; r < 2; ++r) {
        int bb = lane + 64*r;
        double pm = lse_m[bb*K_BEAM + b];
        double ps = lse_s[bb*K_BEAM + b];
        double nm = fmax(m, pm);
        s = s * exp(m - nm) + ps * exp(pm - nm);
        m = nm;
      }
      wave_merge_ms_d(m, s);
      if (lane == 0) lseS[b] = m + log(s);
    }
  }
  __syncthreads();
  // 10 argmax rounds over 12810 candidates
  const float* cvv = ws + CANDV_F;
  const int*   cii = (const int*)(ws + CANDI_F);
  for (int pick = 0; pick < K_BEAM; ++pick) {
    double lv = -1e301; int lf = 0x7ffffff0;
    for (int c = tid; c < NCAND; c += 256) {
      double val; int flat;
      if (c < NREAL) {
        int blk = c / (K_BEAM*10);
        int rem = c - blk*(K_BEAM*10);
        int b = rem / 10, j = rem - b*10;
        int idx = (blk*K_BEAM + b)*10 + j;
        if (finS[b] || (step == 0 && b > 0)) continue;
        flat = b*V_SZ + cii[idx];
        val = scS[b] - lseS[b] + (double)cvv[idx];
      } else {
        int b = c - NREAL;
        if (!finS[b]) continue;
        val = scS[b]; flat = b*V_SZ + EOS_TOK;
      }
      bool ex = false;
      for (int q = 0; q < pick; ++q) ex = ex || (pf[q] == flat);
      if (ex) continue;
      if (val > lv || (val == lv && flat < lf)) { lv = val; lf = flat; }
    }
    sred[tid] = lv; sidx[tid] = lf; __syncthreads();
    for (int s2 = 128; s2 > 0; s2 >>= 1) {
      if (tid < s2) {
        if (sred[tid+s2] > sred[tid] ||
            (sred[tid+s2] == sred[tid] && sidx[tid+s2] < sidx[tid])) {
          sred[tid] = sred[tid+s2]; sidx[tid] = sidx[tid+s2];
        }
      }
      __syncthreads();
    }
    if (tid == 0) { pv[pick] = sred[0]; pf[pick] = sidx[0]; }
    __syncthreads();
  }
  if (tid < K_BEAM) {
    ((double*)(ws + PICKV_F))[tid] = pv[tid];
    ((int*)(ws + PICKF_F))[tid] = pf[tid];
  }
}

// ---------------- final: gather + lengths + output ----------------
__global__ __launch_bounds__(256) void final_kernel(float* ws, float* out) {
  const int tid = threadIdx.x;
  const float* mA = ws + META_A_F;     // dst of ab(29) (odd step -> A)
  const int* seqA = (const int*)(mA + M_SEQ);
  const double* pvv = (const double*)(ws + PICKV_F);
  const int* pfv = (const int*)(ws + PICKF_F);
  __shared__ int seqF[K_BEAM*SEQ_LEN];
  __shared__ int s_tok[K_BEAM], s_pb[K_BEAM];
  if (tid < K_BEAM) {
    int f = pfv[tid];
    int pb = f / V_SZ, tk = f - pb*V_SZ;
    s_pb[tid] = min(max(pb, 0), K_BEAM - 1);
    s_tok[tid] = min(max(tk, 0), V_SZ - 1);
  }
  __syncthreads();
  for (int t = tid; t < K_BEAM*SEQ_LEN; t += 256) {
    int j = t / SEQ_LEN, p = t - j*SEQ_LEN;
    seqF[t] = (p == MAXLEN) ? s_tok[j] : seqA[s_pb[j]*SEQ_LEN + p];
  }
  __syncthreads();
  if (tid < K_BEAM) {
    int first = -1;
    for (int p = 1; p <= MAXLEN; ++p)
      if (seqF[tid*SEQ_LEN + p] == EOS_TOK) { first = p - 1; break; }
    double len = (first >= 0) ? (double)(first + 2) : (double)(MAXLEN + 2);
    double scv = pvv[tid];
    out[K_BEAM*SEQ_LEN + tid] = (float)scv;
    out[K_BEAM*SEQ_LEN + K_BEAM + tid] = (float)(scv / pow(len, 1.2));
  }
  for (int t = tid; t < K_BEAM*SEQ_LEN; t += 256) out[t] = (float)seqF[t];
}

// ---------------- host ----------------
extern "C" void kernel_launch(void* const* d_in, const int* in_sizes, int n_in,
                              void* d_out, int out_size, void* d_ws, size_t ws_size,
                              hipStream_t stream) {
  const float* enc_key    = (const float*)d_in[0];
  const float* enc_values = (const float*)d_in[1];
  const float* maskp      = (const float*)d_in[2];
  const float* embedding  = (const float*)d_in[3];
  const float* W_ih1      = (const float*)d_in[4];
  const float* W_hh1      = (const float*)d_in[5];
  const float* b_ih1      = (const float*)d_in[6];
  const float* b_hh1      = (const float*)d_in[7];
  const float* W_ih2      = (const float*)d_in[8];
  const float* W_hh2      = (const float*)d_in[9];
  const float* b_ih2      = (const float*)d_in[10];
  const float* b_hh2      = (const float*)d_in[11];
  const float* Wq         = (const float*)d_in[12];
  const float* bq         = (const float*)d_in[13];
  const float* Wc         = (const float*)d_in[14];
  const float* bc         = (const float*)d_in[15];
  float* ws  = (float*)d_ws;
  float* out = (float*)d_out;

  init_kernel<<<1, 256, 0, stream>>>(ws);
  for (int i = 0; i < MAXLEN; ++i) {
    ab_kernel<<<K_BEAM, 256, 0, stream>>>(ws, i, enc_key, enc_values, maskp, embedding,
                                          W_ih1, W_hh1, b_ih1, b_hh1,
                                          W_ih2, W_hh2, b_ih2, b_hh2, Wq, bq);
    c_kernel<<<CB, 256, 0, stream>>>(ws, Wc, bc);
    sel_kernel<<<1, 256, 0, stream>>>(ws, i);
  }
  final_kernel<<<1, 256, 0, stream>>>(ws, out);
}

// Round 8
// 9458.549 us; speedup vs baseline: 38.6401x; 1.9477x over previous
//
#include <hip/hip_runtime.h>
#include <math.h>

// ---------------- problem constants ----------------
#define K_BEAM  10
#define V_SZ    50257
#define E_SZ    128
#define H1_SZ   128
#define H2_SZ   64
#define Q_SZ    64
#define T_SZ    2048
#define MAXLEN  30
#define SEQ_LEN 31
#define SOS_TOK 1
#define EOS_TOK 2

#define CB 128              // blocks in c_kernel
#define VC 393              // ceil(V_SZ / CB)
#define NPB (CB*10)         // 1280 staged candidates per beam

// ---------------- workspace layout (float indices; doubles on even idx) ------
#define ST_A_F   0          // double[4480]: h1[10][128],c1[10][128],h2[10][64],c2,ctx
#define ST_B_F   8960
#define SD_H1    0
#define SD_C1    1280
#define SD_H2    2560
#define SD_C2    3200
#define SD_CTX   3840
#define META_A_F 17920      // SC double[10](@0), FIN i32[10](@20), PREV i32[10](@30), SEQ i32[10][31](@40)
#define META_B_F 18272
#define M_SC     0
#define M_FIN    20
#define M_PREV   30
#define M_SEQ    40
#define XVEC_F   18624      // double[10][128]
#define PICKV_F  21184      // double[10]
#define PICKF_F  21204      // int[10]
#define LSEM_F   21216      // double[128][10] partial max
#define LSES_F   23776      // double[128][10] partial sumexp
#define CANDV_F  26336      // float[128][10][10] candidate logits (f32-rounded)
#define CANDI_F  39136      // int[128][10][10] candidate v indices
#define B10V_F   51936      // double[10][10] per-beam top-10 values
#define B10F_F   52136      // int[10][10] per-beam top-10 flat indices
// total ~52240 floats ~= 209 KiB (ws verified >= 2.1 MB in r6)

// ---------------- wave helpers (f64) ----------------
__device__ __forceinline__ void wave_merge_ms_d(double& m, double& s) {
  #pragma unroll
  for (int off = 32; off > 0; off >>= 1) {
    double om = __shfl_down(m, off, 64);
    double os = __shfl_down(s, off, 64);
    double nm = fmax(m, om);
    s = s * exp(m - nm) + os * exp(om - nm);
    m = nm;
  }
}
// argmax: higher value wins; tie -> lower index (jax top_k order)
__device__ __forceinline__ void wave_argmax_f(float& v, int& i) {
  #pragma unroll
  for (int off = 32; off > 0; off >>= 1) {
    float ov = __shfl_down(v, off, 64);
    int   oi = __shfl_down(i, off, 64);
    if (ov > v || (ov == v && oi < i)) { v = ov; i = oi; }
  }
}

// ---------------- init ----------------
__global__ void init_kernel(float* ws) {
  const int tid = threadIdx.x;
  double* stA = (double*)(ws + ST_A_F);
  for (int i = tid; i < 4480; i += 256) stA[i] = 0.0;
  float* mA = ws + META_A_F;
  if (tid < K_BEAM) {
    ((double*)(mA + M_SC))[tid] = 0.0;
    ((int*)(mA + M_FIN))[tid] = 0;
    ((int*)(mA + M_PREV))[tid] = SOS_TOK;
  }
  for (int i = tid; i < K_BEAM*SEQ_LEN; i += 256)
    ((int*)(mA + M_SEQ))[i] = SOS_TOK;
}

// ---------------- per-beam forward: gather + LSTMx2 + attention (f64) --------
__global__ __launch_bounds__(256) void ab_kernel(
    float* ws, int step,
    const float* enc_key, const float* enc_values, const float* maskp,
    const float* embedding,
    const float* W_ih1, const float* W_hh1, const float* b_ih1, const float* b_hh1,
    const float* W_ih2, const float* W_hh2, const float* b_ih2, const float* b_hh2,
    const float* Wq, const float* bq) {
  const int tid = threadIdx.x;
  const int b = blockIdx.x;
  const int par = step & 1;
  const double* S = (const double*)(ws + (par == 0 ? ST_A_F : ST_B_F));
  double*       D = (double*)(ws + (par == 0 ? ST_B_F : ST_A_F));
  const float* msrc = ws + (par == 0 ? META_A_F : META_B_F);
  float*       mdst = ws + (par == 0 ? META_B_F : META_A_F);
  double* xvec = (double*)(ws + XVEC_F);

  __shared__ int s_pb, s_tok;
  if (tid == 0) {
    int pb, tok, fin; double sc;
    if (step == 0) {
      pb = b; tok = ((const int*)(msrc + M_PREV))[b];
      sc = ((const double*)(msrc + M_SC))[b];
      fin = ((const int*)(msrc + M_FIN))[b];
    } else {
      int f = ((const int*)(ws + PICKF_F))[b];
      pb = f / V_SZ; tok = f - pb * V_SZ;
      pb = min(max(pb, 0), K_BEAM - 1);
      tok = min(max(tok, 0), V_SZ - 1);
      sc = ((const double*)(ws + PICKV_F))[b];
      fin = ((const int*)(msrc + M_FIN))[pb] | (tok == EOS_TOK);
    }
    s_pb = pb; s_tok = tok;
    ((double*)(mdst + M_SC))[b] = sc;
    ((int*)(mdst + M_FIN))[b] = fin;
    ((int*)(mdst + M_PREV))[b] = tok;
  }
  __syncthreads();
  const int pb = s_pb, tok = s_tok;
  for (int p = tid; p < SEQ_LEN; p += 256) {
    int v = ((const int*)(msrc + M_SEQ))[pb*SEQ_LEN + p];
    if (step > 0 && p == step) v = tok;
    ((int*)(mdst + M_SEQ))[b*SEQ_LEN + p] = v;
  }

  __shared__ double xin[E_SZ+Q_SZ], h1p[H1_SZ], h2pd[H2_SZ], gt[4*H1_SZ],
                    h1n[H1_SZ], h2n[H2_SZ], qd[Q_SZ], red[256];
  __shared__ double eng[T_SZ];

  if (tid < E_SZ)  xin[tid] = (double)embedding[(size_t)tok*E_SZ + tid];
  if (tid < Q_SZ)  xin[E_SZ + tid] = S[SD_CTX + pb*Q_SZ + tid];
  if (tid < H1_SZ) h1p[tid] = S[SD_H1 + pb*H1_SZ + tid];
  if (tid < H2_SZ) h2pd[tid] = S[SD_H2 + pb*H2_SZ + tid];
  __syncthreads();
  // LSTM1 gates — float4 row loads, exact d order preserved
  for (int r = tid; r < 4*H1_SZ; r += 256) {
    double acc = (double)b_ih1[r] + (double)b_hh1[r];
    const float4* wi = (const float4*)(W_ih1 + (size_t)r*(E_SZ+Q_SZ));
    for (int j = 0; j < (E_SZ+Q_SZ)/4; ++j) {
      float4 w = wi[j];
      acc += (double)w.x * xin[4*j];
      acc += (double)w.y * xin[4*j+1];
      acc += (double)w.z * xin[4*j+2];
      acc += (double)w.w * xin[4*j+3];
    }
    const float4* wh = (const float4*)(W_hh1 + (size_t)r*H1_SZ);
    for (int j = 0; j < H1_SZ/4; ++j) {
      float4 w = wh[j];
      acc += (double)w.x * h1p[4*j];
      acc += (double)w.y * h1p[4*j+1];
      acc += (double)w.z * h1p[4*j+2];
      acc += (double)w.w * h1p[4*j+3];
    }
    gt[r] = acc;
  }
  __syncthreads();
  if (tid < H1_SZ) {
    double ig = 1.0/(1.0+exp(-gt[tid]));
    double fg = 1.0/(1.0+exp(-gt[H1_SZ+tid]));
    double gg = tanh(gt[2*H1_SZ+tid]);
    double og = 1.0/(1.0+exp(-gt[3*H1_SZ+tid]));
    double c = fg * S[SD_C1 + pb*H1_SZ + tid] + ig*gg;
    double h = og * tanh(c);
    D[SD_C1 + b*H1_SZ + tid] = c; D[SD_H1 + b*H1_SZ + tid] = h;
    h1n[tid] = h;
  }
  __syncthreads();
  // LSTM2 gates
  {
    int r = tid;
    double acc = (double)b_ih2[r] + (double)b_hh2[r];
    const float4* wi = (const float4*)(W_ih2 + (size_t)r*H1_SZ);
    for (int j = 0; j < H1_SZ/4; ++j) {
      float4 w = wi[j];
      acc += (double)w.x * h1n[4*j];
      acc += (double)w.y * h1n[4*j+1];
      acc += (double)w.z * h1n[4*j+2];
      acc += (double)w.w * h1n[4*j+3];
    }
    const float4* wh = (const float4*)(W_hh2 + (size_t)r*H2_SZ);
    for (int j = 0; j < H2_SZ/4; ++j) {
      float4 w = wh[j];
      acc += (double)w.x * h2pd[4*j];
      acc += (double)w.y * h2pd[4*j+1];
      acc += (double)w.z * h2pd[4*j+2];
      acc += (double)w.w * h2pd[4*j+3];
    }
    gt[r] = acc;
  }
  __syncthreads();
  if (tid < H2_SZ) {
    double ig = 1.0/(1.0+exp(-gt[tid]));
    double fg = 1.0/(1.0+exp(-gt[H2_SZ+tid]));
    double gg = tanh(gt[2*H2_SZ+tid]);
    double og = 1.0/(1.0+exp(-gt[3*H2_SZ+tid]));
    double c = fg * S[SD_C2 + pb*H2_SZ + tid] + ig*gg;
    double h = og * tanh(c);
    D[SD_C2 + b*H2_SZ + tid] = c; D[SD_H2 + b*H2_SZ + tid] = h;
    h2n[tid] = h;
    xvec[b*128 + tid] = h;
  }
  __syncthreads();
  if (tid < Q_SZ) {
    double acc = (double)bq[tid];
    const float4* wr = (const float4*)(Wq + (size_t)tid*H2_SZ);
    for (int j = 0; j < H2_SZ/4; ++j) {
      float4 w = wr[j];
      acc += (double)w.x * h2n[4*j];
      acc += (double)w.y * h2n[4*j+1];
      acc += (double)w.z * h2n[4*j+2];
      acc += (double)w.w * h2n[4*j+3];
    }
    qd[tid] = acc;
  }
  __syncthreads();
  // attention (literal: softmax, mask, renorm)
  double lm = -1e300;
  for (int t = tid; t < T_SZ; t += 256) {
    const float4* kr = (const float4*)(enc_key + (size_t)t*Q_SZ);
    double e = 0.0;
    for (int j = 0; j < Q_SZ/4; ++j) {
      float4 k = kr[j];
      e += (double)k.x * qd[4*j];
      e += (double)k.y * qd[4*j+1];
      e += (double)k.z * qd[4*j+2];
      e += (double)k.w * qd[4*j+3];
    }
    eng[t] = e; lm = fmax(lm, e);
  }
  red[tid] = lm; __syncthreads();
  for (int s2 = 128; s2 > 0; s2 >>= 1) { if (tid < s2) red[tid] = fmax(red[tid], red[tid+s2]); __syncthreads(); }
  double mx = red[0]; __syncthreads();
  double ls = 0.0;
  for (int t = tid; t < T_SZ; t += 256) ls += exp(eng[t] - mx);
  red[tid] = ls; __syncthreads();
  for (int s2 = 128; s2 > 0; s2 >>= 1) { if (tid < s2) red[tid] += red[tid+s2]; __syncthreads(); }
  double Ssum = red[0]; __syncthreads();
  double lm2 = 0.0;
  for (int t = tid; t < T_SZ; t += 256) {
    double matt = (double)maskp[t] * (exp(eng[t] - mx) / Ssum);
    eng[t] = matt; lm2 += matt;
  }
  red[tid] = lm2; __syncthreads();
  for (int s2 = 128; s2 > 0; s2 >>= 1) { if (tid < s2) red[tid] += red[tid+s2]; __syncthreads(); }
  double msum = fmax(red[0], 2e-30); __syncthreads();
  int v = tid & 63, g4 = tid >> 6;
  double acc = 0.0;
  for (int t = g4; t < T_SZ; t += 4) acc += eng[t] * (double)enc_values[(size_t)t*Q_SZ + v];
  red[tid] = acc; __syncthreads();
  if (g4 == 0) {
    double cv = (red[v] + red[64+v] + red[128+v] + red[192+v]) / msum;
    D[SD_CTX + b*Q_SZ + v] = cv;
    xvec[b*128 + 64 + v] = cv;
  }
}

// ---------------- logits chunk + lse partials + per-beam block top-10 --------
__global__ __launch_bounds__(256) void c_kernel(float* ws, const float* Wc, const float* bc) {
  const int tid = threadIdx.x, bb = blockIdx.x;
  const int v0 = bb*VC, vn = min(VC, V_SZ - v0);
  __shared__ double xs[K_BEAM*128];
  __shared__ float lg[VC*K_BEAM];
  const double* xvec = (const double*)(ws + XVEC_F);
  for (int i = tid; i < K_BEAM*128; i += 256) xs[i] = xvec[i];
  __syncthreads();
  // float4 row loads; per-acc element order identical to verified serial build
  for (int vl = tid; vl < vn; vl += 256) {
    const float4* wr = (const float4*)(Wc + (size_t)(v0+vl)*128);
    double acc[K_BEAM];
    #pragma unroll
    for (int b = 0; b < K_BEAM; ++b) acc[b] = 0.0;
    for (int j = 0; j < 32; ++j) {
      float4 w = wr[j];
      double w0 = (double)w.x, w1 = (double)w.y, w2 = (double)w.z, w3 = (double)w.w;
      #pragma unroll
      for (int b = 0; b < K_BEAM; ++b) acc[b] += w0 * xs[b*128 + 4*j];
      #pragma unroll
      for (int b = 0; b < K_BEAM; ++b) acc[b] += w1 * xs[b*128 + 4*j + 1];
      #pragma unroll
      for (int b = 0; b < K_BEAM; ++b) acc[b] += w2 * xs[b*128 + 4*j + 2];
      #pragma unroll
      for (int b = 0; b < K_BEAM; ++b) acc[b] += w3 * xs[b*128 + 4*j + 3];
    }
    double bcv = (double)bc[v0+vl];
    #pragma unroll
    for (int b = 0; b < K_BEAM; ++b) lg[vl*K_BEAM + b] = (float)(acc[b] + bcv);
  }
  __syncthreads();

  const int lane = tid & 63, w = tid >> 6;
  double* lse_m = (double*)(ws + LSEM_F);
  double* lse_s = (double*)(ws + LSES_F);
  float*  cvv   = ws + CANDV_F;
  int*    cii   = (int*)(ws + CANDI_F);
  for (int b = w; b < K_BEAM; b += 4) {
    double m = -1e300, s = 0.0;
    for (int vl = lane; vl < vn; vl += 64) {
      double val = (double)lg[vl*K_BEAM + b];
      double nm = fmax(m, val);
      s = s * exp(m - nm) + exp(val - nm);
      m = nm;
    }
    wave_merge_ms_d(m, s);
    if (lane == 0) { lse_m[bb*K_BEAM + b] = m; lse_s[bb*K_BEAM + b] = s; }
    int taken[10];
    for (int pick = 0; pick < 10; ++pick) {
      float bv = -3e38f; int bi = 0x7ffffff0;
      for (int vl = lane; vl < vn; vl += 64) {
        bool skip = false;
        for (int q = 0; q < pick; ++q) skip = skip || (taken[q] == vl);
        if (!skip) {
          float val = lg[vl*K_BEAM + b];
          if (val > bv || (val == bv && vl < bi)) { bv = val; bi = vl; }
        }
      }
      float wv = bv; int wi = bi;
      wave_argmax_f(wv, wi);
      wv = __shfl(wv, 0, 64); wi = __shfl(wi, 0, 64);
      taken[pick] = wi;
      wi = min(max(wi, 0), vn - 1);
      if (lane == 0) {
        cvv[(bb*K_BEAM + b)*10 + pick] = wv;
        cii[(bb*K_BEAM + b)*10 + pick] = v0 + wi;
      }
    }
  }
}

// ---------------- per-beam selection: 1280 -> top-10 (LDS-staged, f64) -------
__global__ __launch_bounds__(256) void bsel_kernel(float* ws, int step) {
  const int tid = threadIdx.x;
  const int b = blockIdx.x;
  const int par = step & 1;
  const float* mcur = ws + (par == 0 ? META_B_F : META_A_F);  // written by ab(step)
  __shared__ float s_cv[NPB]; __shared__ int s_ci[NPB];
  __shared__ double s_lm[128], s_ls[128];
  __shared__ double sred[256]; __shared__ int sidx[256];
  __shared__ double pvs[10]; __shared__ int pis[10];

  const double sc = ((const double*)(mcur + M_SC))[b];
  const int fin = ((const int*)(mcur + M_FIN))[b];
  const bool masked = fin || (step == 0 && b > 0);

  // merge 128 lse partials (f64 tree)
  if (tid < 128) {
    s_lm[tid] = ((const double*)(ws + LSEM_F))[tid*K_BEAM + b];
    s_ls[tid] = ((const double*)(ws + LSES_F))[tid*K_BEAM + b];
  }
  // stage this beam's candidates into LDS
  for (int c = tid; c < NPB; c += 256) {
    int blk = c / 10, j = c - blk*10;
    int idx = (blk*K_BEAM + b)*10 + j;
    s_cv[c] = (ws + CANDV_F)[idx];
    s_ci[c] = ((const int*)(ws + CANDI_F))[idx];
  }
  __syncthreads();
  for (int s2 = 64; s2 > 0; s2 >>= 1) {
    if (tid < s2) {
      double m1 = s_lm[tid], m2 = s_lm[tid+s2];
      double nm = fmax(m1, m2);
      s_ls[tid] = s_ls[tid]*exp(m1-nm) + s_ls[tid+s2]*exp(m2-nm);
      s_lm[tid] = nm;
    }
    __syncthreads();
  }
  const double base = sc - (s_lm[0] + log(s_ls[0]));
  __syncthreads();

  // 10 picks over LDS candidates (value desc, v asc); exclusion by v (unique)
  for (int pick = 0; pick < 10; ++pick) {
    double lv = -1e301; int li = 0x7ffffff0;
    if (!masked) {
      for (int c = tid; c < NPB; c += 256) {
        int v = s_ci[c];
        bool ex = false;
        for (int q = 0; q < pick; ++q) ex = ex || (pis[q] == v);
        if (ex) continue;
        double val = base + (double)s_cv[c];
        if (val > lv || (val == lv && v < li)) { lv = val; li = v; }
      }
    }
    sred[tid] = lv; sidx[tid] = li; __syncthreads();
    for (int s2 = 128; s2 > 0; s2 >>= 1) {
      if (tid < s2) {
        if (sred[tid+s2] > sred[tid] ||
            (sred[tid+s2] == sred[tid] && sidx[tid+s2] < sidx[tid])) {
          sred[tid] = sred[tid+s2]; sidx[tid] = sidx[tid+s2];
        }
      }
      __syncthreads();
    }
    if (tid == 0) { pvs[pick] = sred[0]; pis[pick] = sidx[0]; }
    __syncthreads();
  }

  // publish per-beam top-10 (finished beam: single EOS candidate)
  if (tid < 10) {
    double v; int flat;
    if (fin) {
      v = (tid == 0) ? sc : -1e301;
      flat = (tid == 0) ? (b*V_SZ + EOS_TOK) : 0x7ffffff0;
    } else if (step == 0 && b > 0) {
      v = -1e301; flat = 0x7ffffff0;
    } else {
      v = pvs[tid]; flat = b*V_SZ + pis[tid];
    }
    ((double*)(ws + B10V_F))[b*10 + tid] = v;
    ((int*)(ws + B10F_F))[b*10 + tid] = flat;
  }
}

// ---------------- merge 100 -> global top-10 ----------------
__global__ __launch_bounds__(128) void msel_kernel(float* ws) {
  const int tid = threadIdx.x;
  __shared__ double cv[100]; __shared__ int cf[100];
  __shared__ double sred[128]; __shared__ int sidx[128];
  __shared__ int pslot[10];
  if (tid < 100) {
    cv[tid] = ((const double*)(ws + B10V_F))[tid];
    cf[tid] = ((const int*)(ws + B10F_F))[tid];
  }
  __syncthreads();
  for (int pick = 0; pick < 10; ++pick) {
    double lv = -1e302; int ls = 127;            // slot index; cf[slot] for ties
    if (tid < 100) {
      bool ex = false;
      for (int q = 0; q < pick; ++q) ex = ex || (pslot[q] == tid);
      if (!ex) { lv = cv[tid]; ls = tid; }
    }
    sred[tid] = lv; sidx[tid] = ls; __syncthreads();
    for (int s2 = 64; s2 > 0; s2 >>= 1) {
      if (tid < s2) {
        double v2 = sred[tid+s2]; int sl2 = sidx[tid+s2];
        double v1 = sred[tid];    int sl1 = sidx[tid];
        bool take = (v2 > v1);
        if (v2 == v1 && sl2 < 100 && sl1 < 100 && cf[sl2] < cf[sl1]) take = true;
        if (sl1 >= 100) take = (sl2 < 100) || take;
        if (take) { sred[tid] = v2; sidx[tid] = sl2; }
      }
      __syncthreads();
    }
    if (tid == 0) pslot[pick] = sidx[0];
    __syncthreads();
  }
  if (tid < 10) {
    int sl = pslot[tid];
    sl = min(max(sl, 0), 99);
    ((double*)(ws + PICKV_F))[tid] = cv[sl];
    ((int*)(ws + PICKF_F))[tid] = cf[sl];
  }
}

// ---------------- final: gather + lengths + output ----------------
__global__ __launch_bounds__(256) void final_kernel(float* ws, float* out) {
  const int tid = threadIdx.x;
  const float* mA = ws + META_A_F;     // dst of ab(29) (odd step -> A)
  const int* seqA = (const int*)(mA + M_SEQ);
  const double* pvv = (const double*)(ws + PICKV_F);
  const int* pfv = (const int*)(ws + PICKF_F);
  __shared__ int seqF[K_BEAM*SEQ_LEN];
  __shared__ int s_tok[K_BEAM], s_pb[K_BEAM];
  if (tid < K_BEAM) {
    int f = pfv[tid];
    int pb = f / V_SZ, tk = f - pb*V_SZ;
    s_pb[tid] = min(max(pb, 0), K_BEAM - 1);
    s_tok[tid] = min(max(tk, 0), V_SZ - 1);
  }
  __syncthreads();
  for (int t = tid; t < K_BEAM*SEQ_LEN; t += 256) {
    int j = t / SEQ_LEN, p = t - j*SEQ_LEN;
    seqF[t] = (p == MAXLEN) ? s_tok[j] : seqA[s_pb[j]*SEQ_LEN + p];
  }
  __syncthreads();
  if (tid < K_BEAM) {
    int first = -1;
    for (int p = 1; p <= MAXLEN; ++p)
      if (seqF[tid*SEQ_LEN + p] == EOS_TOK) { first = p - 1; break; }
    double len = (first >= 0) ? (double)(first + 2) : (double)(MAXLEN + 2);
    double scv = pvv[tid];
    out[K_BEAM*SEQ_LEN + tid] = (float)scv;
    out[K_BEAM*SEQ_LEN + K_BEAM + tid] = (float)(scv / pow(len, 1.2));
  }
  for (int t = tid; t < K_BEAM*SEQ_LEN; t += 256) out[t] = (float)seqF[t];
}

// ---------------- host ----------------
extern "C" void kernel_launch(void* const* d_in, const int* in_sizes, int n_in,
                              void* d_out, int out_size, void* d_ws, size_t ws_size,
                              hipStream_t stream) {
  const float* enc_key    = (const float*)d_in[0];
  const float* enc_values = (const float*)d_in[1];
  const float* maskp      = (const float*)d_in[2];
  const float* embedding  = (const float*)d_in[3];
  const float* W_ih1      = (const float*)d_in[4];
  const float* W_hh1      = (const float*)d_in[5];
  const float* b_ih1      = (const float*)d_in[6];
  const float* b_hh1      = (const float*)d_in[7];
  const float* W_ih2      = (const float*)d_in[8];
  const float* W_hh2      = (const float*)d_in[9];
  const float* b_ih2      = (const float*)d_in[10];
  const float* b_hh2      = (const float*)d_in[11];
  const float* Wq         = (const float*)d_in[12];
  const float* bq         = (const float*)d_in[13];
  const float* Wc         = (const float*)d_in[14];
  const float* bc         = (const float*)d_in[15];
  float* ws  = (float*)d_ws;
  float* out = (float*)d_out;

  init_kernel<<<1, 256, 0, stream>>>(ws);
  for (int i = 0; i < MAXLEN; ++i) {
    ab_kernel<<<K_BEAM, 256, 0, stream>>>(ws, i, enc_key, enc_values, maskp, embedding,
                                          W_ih1, W_hh1, b_ih1, b_hh1,
                                          W_ih2, W_hh2, b_ih2, b_hh2, Wq, bq);
    c_kernel<<<CB, 256, 0, stream>>>(ws, Wc, bc);
    bsel_kernel<<<K_BEAM, 256, 0, stream>>>(ws, i);
    msel_kernel<<<1, 128, 0, stream>>>(ws);
  }
  final_kernel<<<1, 256, 0, stream>>>(ws, out);
}

// Round 9
// 5485.662 us; speedup vs baseline: 66.6244x; 1.7242x over previous
//
#include <hip/hip_runtime.h>
#include <math.h>

// ---------------- problem constants ----------------
#define K_BEAM  10
#define V_SZ    50257
#define E_SZ    128
#define H1_SZ   128
#define H2_SZ   64
#define Q_SZ    64
#define T_SZ    2048
#define MAXLEN  30
#define SEQ_LEN 31
#define SOS_TOK 1
#define EOS_TOK 2

#define CB 256              // blocks in c_kernel
#define VC 197              // ceil(V_SZ / CB); last block vn = 22
#define NPB (CB*10)         // 2560 staged candidates per beam

// ---------------- workspace layout (float indices; f64 slots at even idx) ----
#define ST_A_F   0          // double[4480]: h1[10][128],c1[10][128],h2[10][64],c2,ctx
#define ST_B_F   8960
#define SD_H1    0
#define SD_C1    1280
#define SD_H2    2560
#define SD_C2    3200
#define SD_CTX   3840
#define META_A_F 17920      // SC double[10](@0), FIN i32[10](@20), PREV i32[10](@30), SEQ i32[10][31](@40)
#define META_B_F 18272
#define M_SC     0
#define M_FIN    20
#define M_PREV   30
#define M_SEQ    40
#define H2V_F    18624      // double[10][64]
#define PICKV_F  19904      // double[10]
#define PICKF_F  19924      // int[10] (+2 pad)
#define GT1_F    19936      // double[10][512] LSTM1 gates
#define QD_F     30176      // double[10][64]  q vectors
#define ENG_F    31456      // double[10][2048] energies
#define MC_F     72416      // double[10][8] chunk max
#define SCC_F    72576      // double[10][8] chunk sumexp
#define MSC_F    72736      // double[10][8] chunk msum
#define CTXC_F   72896      // double[10][8][64] chunk ctx partials
#define LSEM_F   83136      // double[256][10]
#define LSES_F   88256      // double[256][10]
#define CANDV_F  93376      // float[256][10][10]
#define CANDI_F  118976     // int[256][10][10]
#define B10V_F   144576     // double[10][10]
#define B10F_F   144776     // int[10][10]
// total ~145k floats = 580 KiB (< 2.1 MB verified ws)

// ---------------- wave helpers ----------------
__device__ __forceinline__ void wave_merge_ms_d(double& m, double& s) {
  #pragma unroll
  for (int off = 32; off > 0; off >>= 1) {
    double om = __shfl_down(m, off, 64);
    double os = __shfl_down(s, off, 64);
    double nm = fmax(m, om);
    s = s * exp(m - nm) + os * exp(om - nm);
    m = nm;
  }
}
__device__ __forceinline__ void wave_argmax_f(float& v, int& i) {
  #pragma unroll
  for (int off = 32; off > 0; off >>= 1) {
    float ov = __shfl_down(v, off, 64);
    int   oi = __shfl_down(i, off, 64);
    if (ov > v || (ov == v && oi < i)) { v = ov; i = oi; }
  }
}

// ---------------- init ----------------
__global__ void init_kernel(float* ws) {
  const int tid = threadIdx.x;
  double* stA = (double*)(ws + ST_A_F);
  for (int i = tid; i < 4480; i += 256) stA[i] = 0.0;
  float* mA = ws + META_A_F;
  if (tid < K_BEAM) {
    ((double*)(mA + M_SC))[tid] = 0.0;
    ((int*)(mA + M_FIN))[tid] = 0;
    ((int*)(mA + M_PREV))[tid] = SOS_TOK;
  }
  for (int i = tid; i < K_BEAM*SEQ_LEN; i += 256)
    ((int*)(mA + M_SEQ))[i] = SOS_TOK;
}

// ---------------- k1: LSTM1 gates (4 blocks/beam, 2 threads/row) -------------
__global__ __launch_bounds__(256) void lstm1_kernel(
    float* ws, int step, const float* embedding,
    const float* W_ih1, const float* W_hh1, const float* b_ih1, const float* b_hh1) {
  const int tid = threadIdx.x;
  const int bm = blockIdx.x >> 2, q4 = blockIdx.x & 3;
  const int par = step & 1;
  const double* S = (const double*)(ws + (par==0 ? ST_A_F : ST_B_F));
  const float* msrc = ws + (par==0 ? META_A_F : META_B_F);
  float*       mdst = ws + (par==0 ? META_B_F : META_A_F);

  __shared__ int s_pb, s_tok;
  if (tid == 0) {
    int pb, tok, fin; double sc;
    if (step == 0) {
      pb = bm; tok = ((const int*)(msrc+M_PREV))[bm];
      sc = ((const double*)(msrc+M_SC))[bm];
      fin = ((const int*)(msrc+M_FIN))[bm];
    } else {
      int f = ((const int*)(ws+PICKF_F))[bm];
      pb = f / V_SZ; tok = f - pb*V_SZ;
      pb = min(max(pb,0),K_BEAM-1); tok = min(max(tok,0),V_SZ-1);
      sc = ((const double*)(ws+PICKV_F))[bm];
      fin = ((const int*)(msrc+M_FIN))[pb] | (tok==EOS_TOK);
    }
    s_pb = pb; s_tok = tok;
    if (q4 == 0) {
      ((double*)(mdst+M_SC))[bm] = sc;
      ((int*)(mdst+M_FIN))[bm] = fin;
      ((int*)(mdst+M_PREV))[bm] = tok;
    }
  }
  __syncthreads();
  const int pb = s_pb, tok = s_tok;
  if (q4 == 0) {
    for (int p = tid; p < SEQ_LEN; p += 256) {
      int v = ((const int*)(msrc+M_SEQ))[pb*SEQ_LEN+p];
      if (step > 0 && p == step) v = tok;
      ((int*)(mdst+M_SEQ))[bm*SEQ_LEN+p] = v;
    }
  }
  __shared__ double xin[192], h1p[128], lo[128], hi[128];
  if (tid < 128)      xin[tid] = (double)embedding[(size_t)tok*E_SZ + tid];
  else if (tid < 192) xin[tid] = S[SD_CTX + pb*Q_SZ + (tid-128)];
  if (tid < 128)      h1p[tid] = S[SD_H1 + pb*H1_SZ + tid];
  __syncthreads();
  const int lr = tid & 127, half = tid >> 7;
  const int r = q4*128 + lr;
  if (half == 0) {
    double acc = (double)b_ih1[r] + (double)b_hh1[r];
    const float4* wi = (const float4*)(W_ih1 + (size_t)r*192);
    for (int j = 0; j < 40; ++j) {
      float4 w = wi[j];
      acc += (double)w.x * xin[4*j];   acc += (double)w.y * xin[4*j+1];
      acc += (double)w.z * xin[4*j+2]; acc += (double)w.w * xin[4*j+3];
    }
    lo[lr] = acc;
  } else {
    double acc = 0.0;
    const float4* wi = (const float4*)(W_ih1 + (size_t)r*192);
    for (int j = 40; j < 48; ++j) {
      float4 w = wi[j];
      acc += (double)w.x * xin[4*j];   acc += (double)w.y * xin[4*j+1];
      acc += (double)w.z * xin[4*j+2]; acc += (double)w.w * xin[4*j+3];
    }
    const float4* wh = (const float4*)(W_hh1 + (size_t)r*128);
    for (int j = 0; j < 32; ++j) {
      float4 w = wh[j];
      acc += (double)w.x * h1p[4*j];   acc += (double)w.y * h1p[4*j+1];
      acc += (double)w.z * h1p[4*j+2]; acc += (double)w.w * h1p[4*j+3];
    }
    hi[lr] = acc;
  }
  __syncthreads();
  if (tid < 128) ((double*)(ws+GT1_F))[bm*512 + r] = lo[tid] + hi[tid];
}

// ---------------- k2: LSTM1 act + LSTM2 + q (1 block/beam) -------------------
__global__ __launch_bounds__(256) void lstm2q_kernel(
    float* ws, int step, const float* W_ih2, const float* W_hh2,
    const float* b_ih2, const float* b_hh2, const float* Wq, const float* bq) {
  const int tid = threadIdx.x;
  const int b = blockIdx.x;
  const int par = step & 1;
  const double* S = (const double*)(ws + (par==0 ? ST_A_F : ST_B_F));
  double*       D = (double*)(ws + (par==0 ? ST_B_F : ST_A_F));
  __shared__ int s_pb;
  if (tid == 0) {
    int pb;
    if (step == 0) pb = b;
    else {
      int f = ((const int*)(ws+PICKF_F))[b];
      pb = f / V_SZ; pb = min(max(pb,0),K_BEAM-1);
    }
    s_pb = pb;
  }
  __syncthreads();
  const int pb = s_pb;
  __shared__ double h1n[128], h2p[64], gt2[256], h2n[64];
  const double* g1 = (const double*)(ws+GT1_F) + b*512;
  if (tid < 128) {
    double ig = 1.0/(1.0+exp(-g1[tid]));
    double fg = 1.0/(1.0+exp(-g1[128+tid]));
    double gg = tanh(g1[256+tid]);
    double og = 1.0/(1.0+exp(-g1[384+tid]));
    double c = fg * S[SD_C1 + pb*H1_SZ + tid] + ig*gg;
    double h = og * tanh(c);
    D[SD_C1 + b*H1_SZ + tid] = c; D[SD_H1 + b*H1_SZ + tid] = h;
    h1n[tid] = h;
  }
  if (tid < 64) h2p[tid] = S[SD_H2 + pb*H2_SZ + tid];
  __syncthreads();
  {
    int r = tid;
    double acc = (double)b_ih2[r] + (double)b_hh2[r];
    const float4* wi = (const float4*)(W_ih2 + (size_t)r*128);
    for (int j = 0; j < 32; ++j) {
      float4 w = wi[j];
      acc += (double)w.x * h1n[4*j];   acc += (double)w.y * h1n[4*j+1];
      acc += (double)w.z * h1n[4*j+2]; acc += (double)w.w * h1n[4*j+3];
    }
    const float4* wh = (const float4*)(W_hh2 + (size_t)r*64);
    for (int j = 0; j < 16; ++j) {
      float4 w = wh[j];
      acc += (double)w.x * h2p[4*j];   acc += (double)w.y * h2p[4*j+1];
      acc += (double)w.z * h2p[4*j+2]; acc += (double)w.w * h2p[4*j+3];
    }
    gt2[r] = acc;
  }
  __syncthreads();
  if (tid < 64) {
    double ig = 1.0/(1.0+exp(-gt2[tid]));
    double fg = 1.0/(1.0+exp(-gt2[64+tid]));
    double gg = tanh(gt2[128+tid]);
    double og = 1.0/(1.0+exp(-gt2[192+tid]));
    double c = fg * S[SD_C2 + pb*H2_SZ + tid] + ig*gg;
    double h = og * tanh(c);
    D[SD_C2 + b*H2_SZ + tid] = c; D[SD_H2 + b*H2_SZ + tid] = h;
    h2n[tid] = h;
    ((double*)(ws+H2V_F))[b*64+tid] = h;
  }
  __syncthreads();
  if (tid < 64) {
    double acc = (double)bq[tid];
    const float4* wr = (const float4*)(Wq + (size_t)tid*64);
    for (int j = 0; j < 16; ++j) {
      float4 w = wr[j];
      acc += (double)w.x * h2n[4*j];   acc += (double)w.y * h2n[4*j+1];
      acc += (double)w.z * h2n[4*j+2]; acc += (double)w.w * h2n[4*j+3];
    }
    ((double*)(ws+QD_F))[b*64+tid] = acc;
  }
}

// ---------------- k3: energy chunks + online (m,s) partials ------------------
__global__ __launch_bounds__(256) void energy_kernel(float* ws, const float* enc_key) {
  const int tid = threadIdx.x;
  const int bm = blockIdx.x >> 3, ch = blockIdx.x & 7;
  __shared__ double qs[64], rm[256], rs[256];
  if (tid < 64) qs[tid] = ((const double*)(ws+QD_F))[bm*64+tid];
  __syncthreads();
  const int t = ch*256 + tid;
  const float4* kr = (const float4*)(enc_key + (size_t)t*64);
  double e = 0.0;
  for (int j = 0; j < 16; ++j) {
    float4 k = kr[j];
    e += (double)k.x * qs[4*j];   e += (double)k.y * qs[4*j+1];
    e += (double)k.z * qs[4*j+2]; e += (double)k.w * qs[4*j+3];
  }
  ((double*)(ws+ENG_F))[bm*2048 + t] = e;
  rm[tid] = e; rs[tid] = 1.0;
  __syncthreads();
  for (int s2 = 128; s2 > 0; s2 >>= 1) {
    if (tid < s2) {
      double m1 = rm[tid], m2 = rm[tid+s2];
      double nm = fmax(m1, m2);
      rs[tid] = rs[tid]*exp(m1-nm) + rs[tid+s2]*exp(m2-nm);
      rm[tid] = nm;
    }
    __syncthreads();
  }
  if (tid == 0) {
    ((double*)(ws+MC_F))[bm*8+ch]  = rm[0];
    ((double*)(ws+SCC_F))[bm*8+ch] = rs[0];
  }
}

// ---------------- k4: matt + chunk msum/ctx partials -------------------------
__global__ __launch_bounds__(256) void ctx_kernel(float* ws, const float* enc_values,
                                                  const float* maskp) {
  const int tid = threadIdx.x;
  const int bm = blockIdx.x >> 3, ch = blockIdx.x & 7;
  __shared__ double e_s[256], red[256];
  __shared__ double mxS, SsS;
  e_s[tid] = ((const double*)(ws+ENG_F))[bm*2048 + ch*256 + tid];
  if (tid == 0) {
    double m = -1e300, s = 0.0;
    for (int c = 0; c < 8; ++c) {
      double mc = ((const double*)(ws+MC_F))[bm*8+c];
      double sc = ((const double*)(ws+SCC_F))[bm*8+c];
      double nm = fmax(m, mc);
      s = s*exp(m-nm) + sc*exp(mc-nm);
      m = nm;
    }
    mxS = m; SsS = s;
  }
  __syncthreads();
  const double mx = mxS, Ss = SsS;
  const int t = ch*256 + tid;
  double matt = (double)maskp[t] * (exp(e_s[tid]-mx)/Ss);
  red[tid] = matt; __syncthreads();
  for (int s2 = 128; s2 > 0; s2 >>= 1) { if (tid < s2) red[tid] += red[tid+s2]; __syncthreads(); }
  if (tid == 0) ((double*)(ws+MSC_F))[bm*8+ch] = red[0];
  __syncthreads();
  const int v = tid & 63, g4 = tid >> 6;
  double acc = 0.0;
  for (int kk = 0; kk < 64; ++kk) {
    int tl = g4 + 4*kk;
    double mt = (double)maskp[ch*256+tl] * (exp(e_s[tl]-mx)/Ss);
    acc += mt * (double)enc_values[(size_t)(ch*256+tl)*64 + v];
  }
  red[tid] = acc; __syncthreads();
  if (g4 == 0)
    ((double*)(ws+CTXC_F))[(bm*8+ch)*64 + v] = red[v]+red[64+v]+red[128+v]+red[192+v];
}

// ---------------- k5: ctx fold + logits + lse partials + block top-10 --------
__global__ __launch_bounds__(256) void c_kernel(float* ws, int step,
                                                const float* Wc, const float* bc) {
  const int tid = threadIdx.x, bb = blockIdx.x;
  const int par = step & 1;
  double* D = (double*)(ws + (par==0 ? ST_B_F : ST_A_F));
  const int v0 = bb*VC, vn = min(VC, V_SZ - v0);
  __shared__ double xs[K_BEAM*128];
  __shared__ float lg[VC*K_BEAM];
  for (int idx = tid; idx < 640; idx += 256) {
    int b = idx >> 6, v = idx & 63;
    xs[b*128 + v] = ((const double*)(ws+H2V_F))[b*64+v];
    double ms = 0.0;
    for (int c = 0; c < 8; ++c) ms += ((const double*)(ws+MSC_F))[b*8+c];
    ms = fmax(ms, 2e-30);
    double cv = 0.0;
    for (int c = 0; c < 8; ++c) cv += ((const double*)(ws+CTXC_F))[(b*8+c)*64+v];
    cv /= ms;
    xs[b*128 + 64 + v] = cv;
    if (bb == 0) D[SD_CTX + b*64 + v] = cv;   // identical fixed-order computation
  }
  __syncthreads();
  for (int vl = tid; vl < vn; vl += 256) {
    const float4* wr = (const float4*)(Wc + (size_t)(v0+vl)*128);
    double acc[K_BEAM];
    #pragma unroll
    for (int b = 0; b < K_BEAM; ++b) acc[b] = 0.0;
    for (int j = 0; j < 32; ++j) {
      float4 w = wr[j];
      double w0 = (double)w.x, w1 = (double)w.y, w2 = (double)w.z, w3 = (double)w.w;
      #pragma unroll
      for (int b = 0; b < K_BEAM; ++b) acc[b] += w0 * xs[b*128 + 4*j];
      #pragma unroll
      for (int b = 0; b < K_BEAM; ++b) acc[b] += w1 * xs[b*128 + 4*j + 1];
      #pragma unroll
      for (int b = 0; b < K_BEAM; ++b) acc[b] += w2 * xs[b*128 + 4*j + 2];
      #pragma unroll
      for (int b = 0; b < K_BEAM; ++b) acc[b] += w3 * xs[b*128 + 4*j + 3];
    }
    double bcv = (double)bc[v0+vl];
    #pragma unroll
    for (int b = 0; b < K_BEAM; ++b) lg[vl*K_BEAM + b] = (float)(acc[b] + bcv);
  }
  __syncthreads();

  const int lane = tid & 63, w = tid >> 6;
  double* lse_m = (double*)(ws + LSEM_F);
  double* lse_s = (double*)(ws + LSES_F);
  float*  cvv   = ws + CANDV_F;
  int*    cii   = (int*)(ws + CANDI_F);
  for (int b = w; b < K_BEAM; b += 4) {
    double m = -1e300, s = 0.0;
    for (int vl = lane; vl < vn; vl += 64) {
      double val = (double)lg[vl*K_BEAM + b];
      double nm = fmax(m, val);
      s = s * exp(m - nm) + exp(val - nm);
      m = nm;
    }
    wave_merge_ms_d(m, s);
    if (lane == 0) { lse_m[bb*K_BEAM + b] = m; lse_s[bb*K_BEAM + b] = s; }
    int taken[10];
    for (int pick = 0; pick < 10; ++pick) {
      float bv = -3e38f; int bi = 0x7ffffff0;
      for (int vl = lane; vl < vn; vl += 64) {
        bool skip = false;
        for (int q = 0; q < pick; ++q) skip = skip || (taken[q] == vl);
        if (!skip) {
          float val = lg[vl*K_BEAM + b];
          if (val > bv || (val == bv && vl < bi)) { bv = val; bi = vl; }
        }
      }
      float wv = bv; int wi = bi;
      wave_argmax_f(wv, wi);
      wv = __shfl(wv, 0, 64); wi = __shfl(wi, 0, 64);
      taken[pick] = wi;
      wi = min(max(wi, 0), vn - 1);
      if (lane == 0) {
        cvv[(bb*K_BEAM + b)*10 + pick] = wv;
        cii[(bb*K_BEAM + b)*10 + pick] = v0 + wi;
      }
    }
  }
}

// ---------------- per-beam selection: 2560 -> top-10 (LDS, f64) --------------
__global__ __launch_bounds__(256) void bsel_kernel(float* ws, int step) {
  const int tid = threadIdx.x;
  const int b = blockIdx.x;
  const int par = step & 1;
  const float* mcur = ws + (par == 0 ? META_B_F : META_A_F);
  __shared__ float s_cv[NPB]; __shared__ int s_ci[NPB];
  __shared__ double s_lm[256], s_ls[256];
  __shared__ double sred[256]; __shared__ int sidx[256];
  __shared__ double pvs[10]; __shared__ int pis[10];

  const double sc = ((const double*)(mcur + M_SC))[b];
  const int fin = ((const int*)(mcur + M_FIN))[b];
  const bool masked = fin || (step == 0 && b > 0);

  s_lm[tid] = ((const double*)(ws + LSEM_F))[tid*K_BEAM + b];
  s_ls[tid] = ((const double*)(ws + LSES_F))[tid*K_BEAM + b];
  for (int c = tid; c < NPB; c += 256) {
    int blk = c / 10, j = c - blk*10;
    int idx = (blk*K_BEAM + b)*10 + j;
    s_cv[c] = (ws + CANDV_F)[idx];
    s_ci[c] = ((const int*)(ws + CANDI_F))[idx];
  }
  __syncthreads();
  for (int s2 = 128; s2 > 0; s2 >>= 1) {
    if (tid < s2) {
      double m1 = s_lm[tid], m2 = s_lm[tid+s2];
      double nm = fmax(m1, m2);
      s_ls[tid] = s_ls[tid]*exp(m1-nm) + s_ls[tid+s2]*exp(m2-nm);
      s_lm[tid] = nm;
    }
    __syncthreads();
  }
  const double base = sc - (s_lm[0] + log(s_ls[0]));
  __syncthreads();

  for (int pick = 0; pick < 10; ++pick) {
    double lv = -1e301; int li = 0x7ffffff0;
    if (!masked) {
      for (int c = tid; c < NPB; c += 256) {
        int v = s_ci[c];
        bool ex = false;
        for (int q = 0; q < pick; ++q) ex = ex || (pis[q] == v);
        if (ex) continue;
        double val = base + (double)s_cv[c];
        if (val > lv || (val == lv && v < li)) { lv = val; li = v; }
      }
    }
    sred[tid] = lv; sidx[tid] = li; __syncthreads();
    for (int s2 = 128; s2 > 0; s2 >>= 1) {
      if (tid < s2) {
        if (sred[tid+s2] > sred[tid] ||
            (sred[tid+s2] == sred[tid] && sidx[tid+s2] < sidx[tid])) {
          sred[tid] = sred[tid+s2]; sidx[tid] = sidx[tid+s2];
        }
      }
      __syncthreads();
    }
    if (tid == 0) { pvs[pick] = sred[0]; pis[pick] = sidx[0]; }
    __syncthreads();
  }

  if (tid < 10) {
    double v; int flat;
    if (fin) {
      v = (tid == 0) ? sc : -1e301;
      flat = (tid == 0) ? (b*V_SZ + EOS_TOK) : 0x7ffffff0;
    } else if (step == 0 && b > 0) {
      v = -1e301; flat = 0x7ffffff0;
    } else {
      v = pvs[tid]; flat = b*V_SZ + pis[tid];
    }
    ((double*)(ws + B10V_F))[b*10 + tid] = v;
    ((int*)(ws + B10F_F))[b*10 + tid] = flat;
  }
}

// ---------------- merge 100 -> global top-10 ----------------
__global__ __launch_bounds__(128) void msel_kernel(float* ws) {
  const int tid = threadIdx.x;
  __shared__ double cv[100]; __shared__ int cf[100];
  __shared__ double sred[128]; __shared__ int sidx[128];
  __shared__ int pslot[10];
  if (tid < 100) {
    cv[tid] = ((const double*)(ws + B10V_F))[tid];
    cf[tid] = ((const int*)(ws + B10F_F))[tid];
  }
  __syncthreads();
  for (int pick = 0; pick < 10; ++pick) {
    double lv = -1e302; int ls = 127;
    if (tid < 100) {
      bool ex = false;
      for (int q = 0; q < pick; ++q) ex = ex || (pslot[q] == tid);
      if (!ex) { lv = cv[tid]; ls = tid; }
    }
    sred[tid] = lv; sidx[tid] = ls; __syncthreads();
    for (int s2 = 64; s2 > 0; s2 >>= 1) {
      if (tid < s2) {
        double v2 = sred[tid+s2]; int sl2 = sidx[tid+s2];
        double v1 = sred[tid];    int sl1 = sidx[tid];
        bool take = (v2 > v1);
        if (v2 == v1 && sl2 < 100 && sl1 < 100 && cf[sl2] < cf[sl1]) take = true;
        if (sl1 >= 100) take = (sl2 < 100) || take;
        if (take) { sred[tid] = v2; sidx[tid] = sl2; }
      }
      __syncthreads();
    }
    if (tid == 0) pslot[pick] = sidx[0];
    __syncthreads();
  }
  if (tid < 10) {
    int sl = pslot[tid];
    sl = min(max(sl, 0), 99);
    ((double*)(ws + PICKV_F))[tid] = cv[sl];
    ((int*)(ws + PICKF_F))[tid] = cf[sl];
  }
}

// ---------------- final: gather + lengths + output ----------------
__global__ __launch_bounds__(256) void final_kernel(float* ws, float* out) {
  const int tid = threadIdx.x;
  const float* mA = ws + META_A_F;     // dst of step 29 (odd -> A)
  const int* seqA = (const int*)(mA + M_SEQ);
  const double* pvv = (const double*)(ws + PICKV_F);
  const int* pfv = (const int*)(ws + PICKF_F);
  __shared__ int seqF[K_BEAM*SEQ_LEN];
  __shared__ int s_tok[K_BEAM], s_pb[K_BEAM];
  if (tid < K_BEAM) {
    int f = pfv[tid];
    int pb = f / V_SZ, tk = f - pb*V_SZ;
    s_pb[tid] = min(max(pb, 0), K_BEAM - 1);
    s_tok[tid] = min(max(tk, 0), V_SZ - 1);
  }
  __syncthreads();
  for (int t = tid; t < K_BEAM*SEQ_LEN; t += 256) {
    int j = t / SEQ_LEN, p = t - j*SEQ_LEN;
    seqF[t] = (p == MAXLEN) ? s_tok[j] : seqA[s_pb[j]*SEQ_LEN + p];
  }
  __syncthreads();
  if (tid < K_BEAM) {
    int first = -1;
    for (int p = 1; p <= MAXLEN; ++p)
      if (seqF[tid*SEQ_LEN + p] == EOS_TOK) { first = p - 1; break; }
    double len = (first >= 0) ? (double)(first + 2) : (double)(MAXLEN + 2);
    double scv = pvv[tid];
    out[K_BEAM*SEQ_LEN + tid] = (float)scv;
    out[K_BEAM*SEQ_LEN + K_BEAM + tid] = (float)(scv / pow(len, 1.2));
  }
  for (int t = tid; t < K_BEAM*SEQ_LEN; t += 256) out[t] = (float)seqF[t];
}

// ---------------- host ----------------
extern "C" void kernel_launch(void* const* d_in, const int* in_sizes, int n_in,
                              void* d_out, int out_size, void* d_ws, size_t ws_size,
                              hipStream_t stream) {
  const float* enc_key    = (const float*)d_in[0];
  const float* enc_values = (const float*)d_in[1];
  const float* maskp      = (const float*)d_in[2];
  const float* embedding  = (const float*)d_in[3];
  const float* W_ih1      = (const float*)d_in[4];
  const float* W_hh1      = (const float*)d_in[5];
  const float* b_ih1      = (const float*)d_in[6];
  const float* b_hh1      = (const float*)d_in[7];
  const float* W_ih2      = (const float*)d_in[8];
  const float* W_hh2      = (const float*)d_in[9];
  const float* b_ih2      = (const float*)d_in[10];
  const float* b_hh2      = (const float*)d_in[11];
  const float* Wq         = (const float*)d_in[12];
  const float* bq         = (const float*)d_in[13];
  const float* Wc         = (const float*)d_in[14];
  const float* bc         = (const float*)d_in[15];
  float* ws  = (float*)d_ws;
  float* out = (float*)d_out;

  init_kernel<<<1, 256, 0, stream>>>(ws);
  for (int i = 0; i < MAXLEN; ++i) {
    lstm1_kernel<<<4*K_BEAM, 256, 0, stream>>>(ws, i, embedding, W_ih1, W_hh1, b_ih1, b_hh1);
    lstm2q_kernel<<<K_BEAM, 256, 0, stream>>>(ws, i, W_ih2, W_hh2, b_ih2, b_hh2, Wq, bq);
    energy_kernel<<<8*K_BEAM, 256, 0, stream>>>(ws, enc_key);
    ctx_kernel<<<8*K_BEAM, 256, 0, stream>>>(ws, enc_values, maskp);
    c_kernel<<<CB, 256, 0, stream>>>(ws, i, Wc, bc);
    bsel_kernel<<<K_BEAM, 256, 0, stream>>>(ws, i);
    msel_kernel<<<1, 128, 0, stream>>>(ws);
  }
  final_kernel<<<1, 256, 0, stream>>>(ws, out);
}